// Round 13
// baseline (144.658 us; speedup 1.0000x reference)
//
#include <hip/hip_runtime.h>

#define NHEADS 8
#define DKK    32
#define DVV    64
#define NTOK   1024
#define DIM    256

typedef float  f32x4 __attribute__((ext_vector_type(4)));
typedef short  s16x4 __attribute__((ext_vector_type(4)));
typedef short  s16x8 __attribute__((ext_vector_type(8)));
typedef int    i32x4 __attribute__((ext_vector_type(4)));

#define SCALE_QK 0.17677669529663687f   /* 32^-0.5 */

__device__ __forceinline__ unsigned short f2bf(float f) {
    unsigned u = __builtin_bit_cast(unsigned, f);
    u += 0x7FFFu + ((u >> 16) & 1u);          // RNE
    return (unsigned short)(u >> 16);
}

__device__ __forceinline__ unsigned cvt_pk_bf16(float lo, float hi) {
    unsigned r;
    asm("v_cvt_pk_bf16_f32 %0, %1, %2" : "=v"(r) : "v"(lo), "v"(hi));
    return r;
}

__device__ __forceinline__ float gelu(float v) {
    return 0.5f * v * (1.0f + erff(v * 0.70710678118654752f));
}

// ---------------------------------------------------------------------------
// C0: x [b][256][1024] f32 -> xbt [4096 tok][256] bf16 (token-major)
// ---------------------------------------------------------------------------
__global__ __launch_bounds__(256) void conv_x(
    const float* __restrict__ x, short* __restrict__ xbt)
{
    __shared__ short tl[64 * 72];
    const int n0 = blockIdx.x * 64, c0 = blockIdx.y * 64, b = blockIdx.z;
    const int tid = threadIdx.x;
    #pragma unroll
    for (int s = 0; s < 16; ++s) {
        int id = tid + s * 256;
        int cc = id >> 6, nn = id & 63;
        tl[nn * 72 + cc] = (short)f2bf(x[(size_t)b * 262144 + (size_t)(c0 + cc) * 1024 + n0 + nn]);
    }
    __syncthreads();
    #pragma unroll
    for (int s = 0; s < 2; ++s) {
        int id = tid + s * 256;
        int nn = id >> 3, c8 = id & 7;
        *(s16x8*)(xbt + ((size_t)b * 1024 + n0 + nn) * 256 + c0 + c8 * 8) =
            *(const s16x8*)&tl[nn * 72 + c8 * 8];
    }
}

// ---------------------------------------------------------------------------
// C1 (fused): weight converts.
//  blocks [0,128):    wqkvb[1024][256], gamma-folded; k rows * SCALE_QK
//  blocks [128,1152): wmkb fragment-order, gmk-folded
//  blocks [1152,1184): wob[256][1024]
// ---------------------------------------------------------------------------
__global__ __launch_bounds__(256) void conv_weights(
    const float* __restrict__ Wq, const float* __restrict__ gq,
    const float* __restrict__ Wk, const float* __restrict__ gk,
    const float* __restrict__ Wv, const float* __restrict__ gv,
    const float* __restrict__ Wmk, const float* __restrict__ gmk,
    const float* __restrict__ Wo,
    short* __restrict__ wqkvb, short* __restrict__ wmkb, short* __restrict__ wob)
{
    const int bid = blockIdx.x;
    if (bid < 128) {
        const int sub = threadIdx.x >> 5;
        const int row = bid * 8 + sub;
        const int c0  = (threadIdx.x & 31) * 8;
        float g; const float* src;
        if (row < 256)      { g = gq[row];                  src = Wq + (size_t)row * DIM; }
        else if (row < 512) { g = gk[row - 256] * SCALE_QK; src = Wk + (size_t)(row - 256) * DIM; }
        else                { g = gv[row - 512];            src = Wv + (size_t)(row - 512) * DIM; }
        float4 x0 = *(const float4*)(src + c0);
        float4 x1 = *(const float4*)(src + c0 + 4);
        s16x8 o;
        o[0] = (short)f2bf(g * x0.x); o[1] = (short)f2bf(g * x0.y);
        o[2] = (short)f2bf(g * x0.z); o[3] = (short)f2bf(g * x0.w);
        o[4] = (short)f2bf(g * x1.x); o[5] = (short)f2bf(g * x1.y);
        o[6] = (short)f2bf(g * x1.z); o[7] = (short)f2bf(g * x1.w);
        *(s16x8*)(wqkvb + (size_t)row * DIM + c0) = o;
    } else if (bid < 1152) {
        const int gid = (bid - 128) * 256 + threadIdx.x;   // 0..262143
        const int c   = gid & 2047;
        const int t   = (gid >> 11) & 15;
        const int h   = gid >> 15;
        const int df  = c >> 9, ks = (c >> 6) & 7, ln = c & 63;
        const int l15 = ln & 15, lhi = ln >> 4;
        const int row = h * 1024 + t * 64 + df * 16 + l15;
        const int col = ks * 32 + lhi * 8;
        const float g = gmk[row];
        const float* src = Wmk + (size_t)row * DIM + col;
        float4 x0 = *(const float4*)(src);
        float4 x1 = *(const float4*)(src + 4);
        s16x8 o;
        o[0] = (short)f2bf(g * x0.x); o[1] = (short)f2bf(g * x0.y);
        o[2] = (short)f2bf(g * x0.z); o[3] = (short)f2bf(g * x0.w);
        o[4] = (short)f2bf(g * x1.x); o[5] = (short)f2bf(g * x1.y);
        o[6] = (short)f2bf(g * x1.z); o[7] = (short)f2bf(g * x1.w);
        *(s16x8*)(wmkb + (size_t)gid * 8) = o;
    } else {
        const int sub = threadIdx.x >> 5;
        const int row = (bid - 1152) * 8 + sub;
        const int l   = threadIdx.x & 31;
        #pragma unroll
        for (int u = 0; u < 4; ++u) {
            int c = l * 8 + u * 256;
            const float* src = Wo + (size_t)row * 1024 + c;
            float4 x0 = *(const float4*)(src);
            float4 x1 = *(const float4*)(src + 4);
            s16x8 o;
            o[0] = (short)f2bf(x0.x); o[1] = (short)f2bf(x0.y);
            o[2] = (short)f2bf(x0.z); o[3] = (short)f2bf(x0.w);
            o[4] = (short)f2bf(x1.x); o[5] = (short)f2bf(x1.y);
            o[6] = (short)f2bf(x1.z); o[7] = (short)f2bf(x1.w);
            *(s16x8*)(wob + (size_t)row * 1024 + c) = o;
        }
    }
}

// ---------------------------------------------------------------------------
// K1: qkv GEMM.  M=1024 ch, N=4096 tok, K=256.  grid (128,8), 256 thr.
// ---------------------------------------------------------------------------
__global__ __launch_bounds__(256) void qkv_mfma(
    const short* __restrict__ wqkvb, const short* __restrict__ xbt,
    const float* __restrict__ bq, const float* __restrict__ bk,
    const float* __restrict__ bv,
    short* __restrict__ qk_t, short* __restrict__ vvb)
{
    __shared__ __align__(16) short tlds[32 * 136];   // 8,704 B

    const int t0 = blockIdx.x * 32;
    const int c0 = blockIdx.y * 128;
    const int tid  = threadIdx.x;
    const int w    = tid >> 6, lane = tid & 63;
    const int l15  = lane & 15, lhi = lane >> 4;
    const int cob = c0 + w * 32;

    f32x4 acc[2][2];
    #pragma unroll
    for (int mf = 0; mf < 2; ++mf)
        #pragma unroll
        for (int nf = 0; nf < 2; ++nf) acc[mf][nf] = (f32x4){0.f, 0.f, 0.f, 0.f};

    #pragma unroll
    for (int ks = 0; ks < 8; ++ks) {
        s16x8 af[2], bf[2];
        #pragma unroll
        for (int mf = 0; mf < 2; ++mf)
            af[mf] = *(const s16x8*)(wqkvb + (size_t)(cob + mf * 16 + l15) * DIM + ks * 32 + lhi * 8);
        #pragma unroll
        for (int nf = 0; nf < 2; ++nf)
            bf[nf] = *(const s16x8*)(xbt + (size_t)(t0 + nf * 16 + l15) * DIM + ks * 32 + lhi * 8);
        #pragma unroll
        for (int mf = 0; mf < 2; ++mf)
            #pragma unroll
            for (int nf = 0; nf < 2; ++nf)
                acc[mf][nf] = __builtin_amdgcn_mfma_f32_16x16x32_bf16(af[mf], bf[nf], acc[mf][nf], 0, 0, 0);
    }

    float bias[2][4];
    #pragma unroll
    for (int mf = 0; mf < 2; ++mf)
        #pragma unroll
        for (int q = 0; q < 4; ++q) {
            int ch = cob + mf * 16 + lhi * 4 + q;
            bias[mf][q] = (ch < 256) ? bq[ch]
                        : (ch < 512) ? bk[ch - 256] * SCALE_QK
                                     : bv[ch - 512];
        }

    if (c0 < 512) {
        #pragma unroll
        for (int mf = 0; mf < 2; ++mf)
            #pragma unroll
            for (int nf = 0; nf < 2; ++nf) {
                s16x4 pk;
                #pragma unroll
                for (int q = 0; q < 4; ++q)
                    pk[q] = (short)f2bf(acc[mf][nf][q] + bias[mf][q]);
                *(s16x4*)&tlds[(nf * 16 + l15) * 136 + w * 32 + mf * 16 + lhi * 4] = pk;
            }
        __syncthreads();
        #pragma unroll
        for (int s = 0; s < 2; ++s) {
            int id = tid + s * 256;
            int tok = id >> 4, c8 = id & 15;
            *(s16x8*)(qk_t + (size_t)(t0 + tok) * 512 + c0 + c8 * 8) =
                *(const s16x8*)&tlds[tok * 136 + c8 * 8];
        }
    } else {
        #pragma unroll
        for (int mf = 0; mf < 2; ++mf)
            #pragma unroll
            for (int nf = 0; nf < 2; ++nf) {
                int gt = t0 + nf * 16 + l15;
                #pragma unroll
                for (int q = 0; q < 4; ++q) {
                    int vch = cob + mf * 16 + lhi * 4 + q - 512;
                    vvb[(size_t)vch * 4096 + gt] = (short)f2bf(acc[mf][nf][q] + bias[mf][q]);
                }
            }
    }
}

// ---------------------------------------------------------------------------
// K2: fused dual-branch flash attention.  SINGLE-VARIABLE CHANGE vs round 11:
// Wmk A-fragments read DIRECT from L2 (fragment-order, h-affinity) instead of
// LDS staging.  Occupancy pinned to the PROVEN 2 blocks/CU via 64 KiB LDS
// (57,344 B epilogue/pad buffer + 8,192 B pe/bmk) and launch_bounds(256,2)
// (VGPR cap 256 -> no spill).  Per-jc __syncthreads() kept (same lockstep
// regime as round 11).
// ---------------------------------------------------------------------------
__global__ __launch_bounds__(256, 2) void attn_kernel(
    const short* __restrict__ qk_t, const short* __restrict__ vvb,
    const short* __restrict__ wmkb, const float* __restrict__ bmk,
    const float* __restrict__ pos_emb, short* __restrict__ gbuf)
{
    __shared__ __align__(16) short big[28672];       // 57,344 B (epilogue + occupancy pad)
    __shared__ float pe_s[1024];                     //  4,096 B
    __shared__ float bmk_s[1024];                    //  4,096 B  = 65,536 total

    const int flat = blockIdx.x;
    const int h  = flat & 7;
    const int it = (flat >> 3) & 15;
    const int b  = flat >> 7;
    const int i0 = it * 64;
    const int tid = threadIdx.x;
    const int w = tid >> 6, lane = tid & 63;
    const int l15 = lane & 15, lhi = lane >> 4;

    for (int p = tid; p < 1024; p += 256) {
        pe_s[p]  = pos_emb[p * NHEADS + h] * 5.656854249492380f;  // * sqrt(32)
        bmk_s[p] = bmk[h * NTOK + p];
    }
    // touch pad so it is not stripped
    if (tid == 0) big[16384] = 0;

    // Q fragments (B-operands): one i-row per lane
    const int irow = i0 + w * 16 + l15;
    const short* q1row = qk_t + ((size_t)b * NTOK + irow) * 512;
    s16x8 a1[8];
    #pragma unroll
    for (int ks = 0; ks < 8; ++ks)
        a1[ks] = *(const s16x8*)(q1row + ks * 32 + lhi * 8);
    s16x8 a2 = *(const s16x8*)(q1row + h * DKK + lhi * 8);

    const int ix = irow >> 5, iy = irow & 31;
    int dyv0[4], dyv1[4];
    #pragma unroll
    for (int q = 0; q < 4; ++q) {
        int j0y = lhi * 4 + q, j1y = 16 + lhi * 4 + q;
        dyv0[q] = (iy >= j0y) ? iy - j0y : j0y - iy;
        dyv1[q] = (iy >= j1y) ? iy - j1y : j1y - iy;
    }

    f32x4 o1[4], o2[4];
    #pragma unroll
    for (int df = 0; df < 4; ++df) { o1[df] = (f32x4){0.f,0.f,0.f,0.f}; o2[df] = (f32x4){0.f,0.f,0.f,0.f}; }
    float m1 = -INFINITY, l1 = 0.0f, m2 = -INFINITY, l2 = 0.0f;

    const short* kbase = qk_t + (size_t)b * NTOK * 512 + 256 + h * DKK;
    const short* vbase = vvb + (size_t)(h * DVV) * 4096 + b * NTOK;
    const short* wtile = wmkb + (size_t)(h * 16) * 16384 + lane * 8;  // per-lane base

    __syncthreads();   // pe_s / bmk_s ready

    for (int jc = 0; jc < 16; ++jc) {
        const int j0 = jc * 64;
        const short* wj = wtile + (size_t)jc * 16384;

        // K and V fragments from global (L2-resident)
        s16x8 b2a[4], vf[2][4];
        #pragma unroll
        for (int df = 0; df < 4; ++df) {
            b2a[df] = *(const s16x8*)(kbase + (size_t)(j0 + df * 16 + l15) * 512 + lhi * 8);
            #pragma unroll
            for (int kt = 0; kt < 2; ++kt)
                vf[kt][df] = *(const s16x8*)(vbase + (size_t)(df * 16 + l15) * 4096 + j0 + kt * 32 + lhi * 8);
        }

        // ---- branch 1: S1^T = Wmk . q1^T  (K=256), A-frags direct from L2 ----
        f32x4 s1T[4];
        #pragma unroll
        for (int df = 0; df < 4; ++df) {
            f32x4 acc = {0.f, 0.f, 0.f, 0.f};
            #pragma unroll
            for (int ks = 0; ks < 8; ++ks) {
                s16x8 afr = *(const s16x8*)(wj + df * 4096 + ks * 512);
                acc = __builtin_amdgcn_mfma_f32_16x16x32_bf16(afr, a1[ks], acc, 0, 0, 0);
            }
            s1T[df] = acc;
        }
        // ---- branch 2: S2^T = k~ . q^T  (K=32, SCALE pre-folded) ----
        f32x4 s2T[4];
        #pragma unroll
        for (int df = 0; df < 4; ++df) {
            f32x4 z = {0.f, 0.f, 0.f, 0.f};
            s2T[df] = __builtin_amdgcn_mfma_f32_16x16x32_bf16(b2a[df], a2, z, 0, 0, 0);
        }

        // bias for branch 1: bmk + pos_emb[|dx|,|dy|]*sqrt(32)
        {
            const int jx0 = j0 >> 5;
            int d0 = ix - jx0;     d0 = d0 < 0 ? -d0 : d0;
            int d1 = ix - jx0 - 1; d1 = d1 < 0 ? -d1 : d1;
            const float* per0 = pe_s + d0 * 32;
            const float* per1 = pe_s + d1 * 32;
            #pragma unroll
            for (int df = 0; df < 4; ++df) {
                f32x4 bm4 = *(const f32x4*)&bmk_s[j0 + df * 16 + lhi * 4];
                #pragma unroll
                for (int q = 0; q < 4; ++q) {
                    int dy = (df & 1) ? dyv1[q] : dyv0[q];
                    float pv = (df < 2) ? per0[dy] : per1[dy];
                    s1T[df][q] += bm4[q] + pv;
                }
            }
        }

        // ---- softmax branch 1 (defer-max, THR=8) ----
        unsigned pk1[4][2];
        {
            float mx = s1T[0][0];
            #pragma unroll
            for (int df = 0; df < 4; ++df)
                #pragma unroll
                for (int q = 0; q < 4; ++q) mx = fmaxf(mx, s1T[df][q]);
            mx = fmaxf(mx, __shfl_xor(mx, 16));
            mx = fmaxf(mx, __shfl_xor(mx, 32));
            float tm = fmaxf(m1, mx);
            if (!__all(tm - m1 <= 8.0f)) {
                float sc = __expf(m1 - tm);
                l1 *= sc;
                #pragma unroll
                for (int df = 0; df < 4; ++df) o1[df] *= sc;
                m1 = tm;
            }
            float rs = 0.f;
            #pragma unroll
            for (int df = 0; df < 4; ++df) {
                float p0 = __expf(s1T[df][0] - m1), p1 = __expf(s1T[df][1] - m1);
                float p2 = __expf(s1T[df][2] - m1), p3 = __expf(s1T[df][3] - m1);
                rs += (p0 + p1) + (p2 + p3);
                pk1[df][0] = cvt_pk_bf16(p0, p1);
                pk1[df][1] = cvt_pk_bf16(p2, p3);
            }
            rs += __shfl_xor(rs, 16);
            rs += __shfl_xor(rs, 32);
            l1 += rs;
        }
        // ---- softmax branch 2 ----
        unsigned pk2[4][2];
        {
            float mx = s2T[0][0];
            #pragma unroll
            for (int df = 0; df < 4; ++df)
                #pragma unroll
                for (int q = 0; q < 4; ++q) mx = fmaxf(mx, s2T[df][q]);
            mx = fmaxf(mx, __shfl_xor(mx, 16));
            mx = fmaxf(mx, __shfl_xor(mx, 32));
            float tm = fmaxf(m2, mx);
            if (!__all(tm - m2 <= 8.0f)) {
                float sc = __expf(m2 - tm);
                l2 *= sc;
                #pragma unroll
                for (int df = 0; df < 4; ++df) o2[df] *= sc;
                m2 = tm;
            }
            float rs = 0.f;
            #pragma unroll
            for (int df = 0; df < 4; ++df) {
                float p0 = __expf(s2T[df][0] - m2), p1 = __expf(s2T[df][1] - m2);
                float p2 = __expf(s2T[df][2] - m2), p3 = __expf(s2T[df][3] - m2);
                rs += (p0 + p1) + (p2 + p3);
                pk2[df][0] = cvt_pk_bf16(p0, p1);
                pk2[df][1] = cvt_pk_bf16(p2, p3);
            }
            rs += __shfl_xor(rs, 16);
            rs += __shfl_xor(rs, 32);
            l2 += rs;
        }

        // ---- PV: O^T += V^T . P^T ; in-register P redistribution ----
        const int srcA = l15 + ((lane & 16) << 1);   // l15 + 32*(lhi&1)
        const bool hi = (lane & 32) != 0;
        #pragma unroll
        for (int kt = 0; kt < 2; ++kt) {
            int x0 = __shfl((int)pk1[2*kt][0], srcA),      x1 = __shfl((int)pk1[2*kt+1][0], srcA);
            int y0 = __shfl((int)pk1[2*kt][1], srcA),      y1 = __shfl((int)pk1[2*kt+1][1], srcA);
            int z0 = __shfl((int)pk1[2*kt][0], srcA + 16), z1 = __shfl((int)pk1[2*kt+1][0], srcA + 16);
            int u0 = __shfl((int)pk1[2*kt][1], srcA + 16), u1 = __shfl((int)pk1[2*kt+1][1], srcA + 16);
            i32x4 bd1 = { hi ? x1 : x0, hi ? y1 : y0, hi ? z1 : z0, hi ? u1 : u0 };
            s16x8 pb1 = __builtin_bit_cast(s16x8, bd1);

            x0 = __shfl((int)pk2[2*kt][0], srcA);      x1 = __shfl((int)pk2[2*kt+1][0], srcA);
            y0 = __shfl((int)pk2[2*kt][1], srcA);      y1 = __shfl((int)pk2[2*kt+1][1], srcA);
            z0 = __shfl((int)pk2[2*kt][0], srcA + 16); z1 = __shfl((int)pk2[2*kt+1][0], srcA + 16);
            u0 = __shfl((int)pk2[2*kt][1], srcA + 16); u1 = __shfl((int)pk2[2*kt+1][1], srcA + 16);
            i32x4 bd2 = { hi ? x1 : x0, hi ? y1 : y0, hi ? z1 : z0, hi ? u1 : u0 };
            s16x8 pb2 = __builtin_bit_cast(s16x8, bd2);

            #pragma unroll
            for (int df = 0; df < 4; ++df)
                o1[df] = __builtin_amdgcn_mfma_f32_16x16x32_bf16(vf[kt][df], pb1, o1[df], 0, 0, 0);
            #pragma unroll
            for (int df = 0; df < 4; ++df)
                o2[df] = __builtin_amdgcn_mfma_f32_16x16x32_bf16(vf[kt][df], pb2, o2[df], 0, 0, 0);
        }

        __syncthreads();   // keep waves lockstep (round-11 timing regime)
    }

    // ---- epilogue: normalize, GELU, LDS-transpose, bf16 token-major store ----
    short* osw = big;                   // overlay [64][72]
    #pragma unroll
    for (int pass = 0; pass < 2; ++pass) {
        __syncthreads();
        const int chbase = (pass ? 512 : 0) + h * DVV;
        const float inv = 1.0f / (pass ? l2 : l1);
        #pragma unroll
        for (int df = 0; df < 4; ++df)
            #pragma unroll
            for (int r = 0; r < 2; ++r) {
                float v0 = gelu((pass ? o2 : o1)[df][2*r]     * inv);
                float v1 = gelu((pass ? o2 : o1)[df][2*r + 1] * inv);
                unsigned d = cvt_pk_bf16(v0, v1);
                *(unsigned*)&osw[(w * 16 + l15) * 72 + df * 16 + lhi * 4 + 2 * r] = d;
            }
        __syncthreads();
        {
            int i = tid >> 2, cb = (tid & 3) * 16;
            s16x8 v0 = *(const s16x8*)&osw[i * 72 + cb];
            s16x8 v1 = *(const s16x8*)&osw[i * 72 + cb + 8];
            size_t dst = ((size_t)b * NTOK + i0 + i) * 1024 + chbase + cb;
            *(s16x8*)(gbuf + dst)     = v0;
            *(s16x8*)(gbuf + dst + 8) = v1;
        }
    }
}

// ---------------------------------------------------------------------------
// K3: out GEMM.  M=256 co, N=4096 tok, K=1024.  grid (128,8) = 1024 blocks
// (4/CU), block 256 (4 waves), tile 32co x 32tok, wave does 16x16.
// ---------------------------------------------------------------------------
__global__ __launch_bounds__(256) void out_mfma(
    const short* __restrict__ wob, const short* __restrict__ gbuf,
    const float* __restrict__ bo, const float* __restrict__ go,
    const float* __restrict__ bo2, float* __restrict__ out)
{
    const int t0 = blockIdx.x * 32;
    const int c0 = blockIdx.y * 32;
    const int tid  = threadIdx.x;
    const int w    = tid >> 6, lane = tid & 63;
    const int l15  = lane & 15, lhi = lane >> 4;
    const int cob = c0 + (w >> 1) * 16;
    const int tob = t0 + (w & 1) * 16;

    f32x4 acc = (f32x4){0.f, 0.f, 0.f, 0.f};

    #pragma unroll 4
    for (int ks = 0; ks < 32; ++ks) {
        s16x8 af = *(const s16x8*)(wob + (size_t)(cob + l15) * 1024 + ks * 32 + lhi * 8);
        s16x8 bf = *(const s16x8*)(gbuf + (size_t)(tob + l15) * 1024 + ks * 32 + lhi * 8);
        acc = __builtin_amdgcn_mfma_f32_16x16x32_bf16(af, bf, acc, 0, 0, 0);
    }

    const int gt = tob + l15;
    const int bb = gt >> 10, n = gt & 1023;
    #pragma unroll
    for (int q = 0; q < 4; ++q) {
        int co = cob + lhi * 4 + q;
        out[(size_t)bb * 262144 + (size_t)co * 1024 + n] =
            fmaf(acc[q] + bo[co], go[co], bo2[co]);
    }
}

// ---------------------------------------------------------------------------
extern "C" void kernel_launch(void* const* d_in, const int* in_sizes, int n_in,
                              void* d_out, int out_size, void* d_ws, size_t ws_size,
                              hipStream_t stream)
{
    const float* x    = (const float*)d_in[0];
    const float* Wq   = (const float*)d_in[1];
    const float* gq   = (const float*)d_in[2];
    const float* bq   = (const float*)d_in[3];
    const float* Wk   = (const float*)d_in[4];
    const float* gk   = (const float*)d_in[5];
    const float* bk   = (const float*)d_in[6];
    const float* Wv   = (const float*)d_in[7];
    const float* gv   = (const float*)d_in[8];
    const float* bv   = (const float*)d_in[9];
    const float* Wmk  = (const float*)d_in[10];
    const float* gmk  = (const float*)d_in[11];
    const float* bmk  = (const float*)d_in[12];
    const float* pe   = (const float*)d_in[13];
    const float* Wo   = (const float*)d_in[14];
    const float* bo   = (const float*)d_in[15];
    const float* go   = (const float*)d_in[16];
    const float* bo2  = (const float*)d_in[17];
    float* out = (float*)d_out;

    char* base = (char*)d_ws;
    short* xbt   = (short*)(base);                     //  2.0 MB
    short* wqkvb = (short*)(base + (2u  << 20));       //  0.5 MB
    short* wmkb  = (short*)(base + (3u  << 20));       //  4.0 MB
    short* wob   = (short*)(base + (7u  << 20));       //  0.5 MB
    short* qk_t  = (short*)(base + (8u  << 20));       //  4.0 MB
    short* vvb   = (short*)(base + (12u << 20));       //  4.0 MB
    short* gbuf  = (short*)(base + (16u << 20));       //  8.0 MB

    conv_x<<<dim3(16, 4, 4), 256, 0, stream>>>(x, xbt);
    conv_weights<<<dim3(1184), 256, 0, stream>>>(Wq, gq, Wk, gk, Wv, gv,
                                                 Wmk, gmk, Wo, wqkvb, wmkb, wob);
    qkv_mfma<<<dim3(128, 8), 256, 0, stream>>>(wqkvb, xbt, bq, bk, bv, qk_t, vvb);
    attn_kernel<<<dim3(512), 256, 0, stream>>>(qk_t, vvb, wmkb, bmk, pe, gbuf);
    out_mfma<<<dim3(128, 8), 256, 0, stream>>>(wob, gbuf, bo, go, bo2, out);
}

// Round 14
// 122.388 us; speedup vs baseline: 1.1820x; 1.1820x over previous
//
#include <hip/hip_runtime.h>

#define NHEADS 8
#define DKK    32
#define DVV    64
#define NTOK   1024
#define DIM    256

typedef float  f32x4 __attribute__((ext_vector_type(4)));
typedef short  s16x4 __attribute__((ext_vector_type(4)));
typedef short  s16x8 __attribute__((ext_vector_type(8)));
typedef int    i32x4 __attribute__((ext_vector_type(4)));

#define SCALE_QK 0.17677669529663687f   /* 32^-0.5 */

__device__ __forceinline__ unsigned short f2bf(float f) {
    unsigned u = __builtin_bit_cast(unsigned, f);
    u += 0x7FFFu + ((u >> 16) & 1u);          // RNE
    return (unsigned short)(u >> 16);
}

__device__ __forceinline__ unsigned cvt_pk_bf16(float lo, float hi) {
    unsigned r;
    asm("v_cvt_pk_bf16_f32 %0, %1, %2" : "=v"(r) : "v"(lo), "v"(hi));
    return r;
}

__device__ __forceinline__ float gelu(float v) {
    return 0.5f * v * (1.0f + erff(v * 0.70710678118654752f));
}

// ---------------------------------------------------------------------------
// C (fused): input + weight converts, one launch, 1440 blocks.
//  blocks [0,256):     x [b][256][1024] f32 -> xbt [4096 tok][256] bf16
//  blocks [256,384):   wqkvb[1024][256], gamma-folded; k rows * SCALE_QK
//  blocks [384,1408):  wmkb fragment-order, gmk-folded
//  blocks [1408,1440): wob[256][1024]
// ---------------------------------------------------------------------------
__global__ __launch_bounds__(256) void conv_all(
    const float* __restrict__ x,
    const float* __restrict__ Wq, const float* __restrict__ gq,
    const float* __restrict__ Wk, const float* __restrict__ gk,
    const float* __restrict__ Wv, const float* __restrict__ gv,
    const float* __restrict__ Wmk, const float* __restrict__ gmk,
    const float* __restrict__ Wo,
    short* __restrict__ xbt, short* __restrict__ wqkvb,
    short* __restrict__ wmkb, short* __restrict__ wob)
{
    __shared__ short tl[64 * 72];
    const int bid = blockIdx.x;
    const int tid = threadIdx.x;
    if (bid < 256) {
        const int n0 = (bid & 15) * 64, c0 = ((bid >> 4) & 3) * 64, b = bid >> 6;
        #pragma unroll
        for (int s = 0; s < 16; ++s) {
            int id = tid + s * 256;
            int cc = id >> 6, nn = id & 63;
            tl[nn * 72 + cc] = (short)f2bf(x[(size_t)b * 262144 + (size_t)(c0 + cc) * 1024 + n0 + nn]);
        }
        __syncthreads();
        #pragma unroll
        for (int s = 0; s < 2; ++s) {
            int id = tid + s * 256;
            int nn = id >> 3, c8 = id & 7;
            *(s16x8*)(xbt + ((size_t)b * 1024 + n0 + nn) * 256 + c0 + c8 * 8) =
                *(const s16x8*)&tl[nn * 72 + c8 * 8];
        }
    } else if (bid < 384) {
        const int sub = tid >> 5;
        const int row = (bid - 256) * 8 + sub;
        const int c0  = (tid & 31) * 8;
        float g; const float* src;
        if (row < 256)      { g = gq[row];                  src = Wq + (size_t)row * DIM; }
        else if (row < 512) { g = gk[row - 256] * SCALE_QK; src = Wk + (size_t)(row - 256) * DIM; }
        else                { g = gv[row - 512];            src = Wv + (size_t)(row - 512) * DIM; }
        float4 x0 = *(const float4*)(src + c0);
        float4 x1 = *(const float4*)(src + c0 + 4);
        s16x8 o;
        o[0] = (short)f2bf(g * x0.x); o[1] = (short)f2bf(g * x0.y);
        o[2] = (short)f2bf(g * x0.z); o[3] = (short)f2bf(g * x0.w);
        o[4] = (short)f2bf(g * x1.x); o[5] = (short)f2bf(g * x1.y);
        o[6] = (short)f2bf(g * x1.z); o[7] = (short)f2bf(g * x1.w);
        *(s16x8*)(wqkvb + (size_t)row * DIM + c0) = o;
    } else if (bid < 1408) {
        const int gid = (bid - 384) * 256 + tid;           // 0..262143
        const int c   = gid & 2047;
        const int t   = (gid >> 11) & 15;
        const int h   = gid >> 15;
        const int df  = c >> 9, ks = (c >> 6) & 7, ln = c & 63;
        const int l15 = ln & 15, lhi = ln >> 4;
        const int row = h * 1024 + t * 64 + df * 16 + l15;
        const int col = ks * 32 + lhi * 8;
        const float g = gmk[row];
        const float* src = Wmk + (size_t)row * DIM + col;
        float4 x0 = *(const float4*)(src);
        float4 x1 = *(const float4*)(src + 4);
        s16x8 o;
        o[0] = (short)f2bf(g * x0.x); o[1] = (short)f2bf(g * x0.y);
        o[2] = (short)f2bf(g * x0.z); o[3] = (short)f2bf(g * x0.w);
        o[4] = (short)f2bf(g * x1.x); o[5] = (short)f2bf(g * x1.y);
        o[6] = (short)f2bf(g * x1.z); o[7] = (short)f2bf(g * x1.w);
        *(s16x8*)(wmkb + (size_t)gid * 8) = o;
    } else {
        const int sub = tid >> 5;
        const int row = (bid - 1408) * 8 + sub;
        const int l   = tid & 31;
        #pragma unroll
        for (int u = 0; u < 4; ++u) {
            int c = l * 8 + u * 256;
            const float* src = Wo + (size_t)row * 1024 + c;
            float4 x0 = *(const float4*)(src);
            float4 x1 = *(const float4*)(src + 4);
            s16x8 o;
            o[0] = (short)f2bf(x0.x); o[1] = (short)f2bf(x0.y);
            o[2] = (short)f2bf(x0.z); o[3] = (short)f2bf(x0.w);
            o[4] = (short)f2bf(x1.x); o[5] = (short)f2bf(x1.y);
            o[6] = (short)f2bf(x1.z); o[7] = (short)f2bf(x1.w);
            *(s16x8*)(wob + (size_t)row * 1024 + c) = o;
        }
    }
}

// ---------------------------------------------------------------------------
// K1: qkv GEMM.  M=1024 ch, N=4096 tok, K=256.  grid (128,8), 256 thr.
// ---------------------------------------------------------------------------
__global__ __launch_bounds__(256) void qkv_mfma(
    const short* __restrict__ wqkvb, const short* __restrict__ xbt,
    const float* __restrict__ bq, const float* __restrict__ bk,
    const float* __restrict__ bv,
    short* __restrict__ qk_t, short* __restrict__ vvb)
{
    __shared__ __align__(16) short tlds[32 * 136];   // 8,704 B

    const int t0 = blockIdx.x * 32;
    const int c0 = blockIdx.y * 128;
    const int tid  = threadIdx.x;
    const int w    = tid >> 6, lane = tid & 63;
    const int l15  = lane & 15, lhi = lane >> 4;
    const int cob = c0 + w * 32;

    f32x4 acc[2][2];
    #pragma unroll
    for (int mf = 0; mf < 2; ++mf)
        #pragma unroll
        for (int nf = 0; nf < 2; ++nf) acc[mf][nf] = (f32x4){0.f, 0.f, 0.f, 0.f};

    #pragma unroll
    for (int ks = 0; ks < 8; ++ks) {
        s16x8 af[2], bf[2];
        #pragma unroll
        for (int mf = 0; mf < 2; ++mf)
            af[mf] = *(const s16x8*)(wqkvb + (size_t)(cob + mf * 16 + l15) * DIM + ks * 32 + lhi * 8);
        #pragma unroll
        for (int nf = 0; nf < 2; ++nf)
            bf[nf] = *(const s16x8*)(xbt + (size_t)(t0 + nf * 16 + l15) * DIM + ks * 32 + lhi * 8);
        #pragma unroll
        for (int mf = 0; mf < 2; ++mf)
            #pragma unroll
            for (int nf = 0; nf < 2; ++nf)
                acc[mf][nf] = __builtin_amdgcn_mfma_f32_16x16x32_bf16(af[mf], bf[nf], acc[mf][nf], 0, 0, 0);
    }

    float bias[2][4];
    #pragma unroll
    for (int mf = 0; mf < 2; ++mf)
        #pragma unroll
        for (int q = 0; q < 4; ++q) {
            int ch = cob + mf * 16 + lhi * 4 + q;
            bias[mf][q] = (ch < 256) ? bq[ch]
                        : (ch < 512) ? bk[ch - 256] * SCALE_QK
                                     : bv[ch - 512];
        }

    if (c0 < 512) {
        #pragma unroll
        for (int mf = 0; mf < 2; ++mf)
            #pragma unroll
            for (int nf = 0; nf < 2; ++nf) {
                s16x4 pk;
                #pragma unroll
                for (int q = 0; q < 4; ++q)
                    pk[q] = (short)f2bf(acc[mf][nf][q] + bias[mf][q]);
                *(s16x4*)&tlds[(nf * 16 + l15) * 136 + w * 32 + mf * 16 + lhi * 4] = pk;
            }
        __syncthreads();
        #pragma unroll
        for (int s = 0; s < 2; ++s) {
            int id = tid + s * 256;
            int tok = id >> 4, c8 = id & 15;
            *(s16x8*)(qk_t + (size_t)(t0 + tok) * 512 + c0 + c8 * 8) =
                *(const s16x8*)&tlds[tok * 136 + c8 * 8];
        }
    } else {
        #pragma unroll
        for (int mf = 0; mf < 2; ++mf)
            #pragma unroll
            for (int nf = 0; nf < 2; ++nf) {
                int gt = t0 + nf * 16 + l15;
                #pragma unroll
                for (int q = 0; q < 4; ++q) {
                    int vch = cob + mf * 16 + lhi * 4 + q - 512;
                    vvb[(size_t)vch * 4096 + gt] = (short)f2bf(acc[mf][nf][q] + bias[mf][q]);
                }
            }
    }
}

// ---------------------------------------------------------------------------
// K2: fused dual-branch flash attention (round-11 proven version, unchanged).
// Online softmax, defer-rescale THR=8.  Double-buffered fragment-order Wmk,
// one barrier per jc.  grid 512, block 256, 2 blocks/CU.
// ---------------------------------------------------------------------------
__global__ __launch_bounds__(256, 2) void attn_kernel(
    const short* __restrict__ qk_t, const short* __restrict__ vvb,
    const short* __restrict__ wmkb, const float* __restrict__ bmk,
    const float* __restrict__ pos_emb, short* __restrict__ gbuf)
{
    __shared__ __align__(16) short wmks[2][16384];   // 65,536 B (2x frag-order)
    __shared__ float pe_s[1024];                     //  4,096 B
    __shared__ float bmk_s[1024];                    //  4,096 B  = 73,728 total

    const int flat = blockIdx.x;
    const int h  = flat & 7;
    const int it = (flat >> 3) & 15;
    const int b  = flat >> 7;
    const int i0 = it * 64;
    const int tid = threadIdx.x;
    const int w = tid >> 6, lane = tid & 63;
    const int l15 = lane & 15, lhi = lane >> 4;

    for (int p = tid; p < 1024; p += 256) {
        pe_s[p]  = pos_emb[p * NHEADS + h] * 5.656854249492380f;  // * sqrt(32)
        bmk_s[p] = bmk[h * NTOK + p];
    }

    // Q fragments (B-operands): one i-row per lane
    const int irow = i0 + w * 16 + l15;
    const short* q1row = qk_t + ((size_t)b * NTOK + irow) * 512;
    s16x8 a1[8];
    #pragma unroll
    for (int ks = 0; ks < 8; ++ks)
        a1[ks] = *(const s16x8*)(q1row + ks * 32 + lhi * 8);
    s16x8 a2 = *(const s16x8*)(q1row + h * DKK + lhi * 8);

    const int ix = irow >> 5, iy = irow & 31;
    int dyv0[4], dyv1[4];
    #pragma unroll
    for (int q = 0; q < 4; ++q) {
        int j0y = lhi * 4 + q, j1y = 16 + lhi * 4 + q;
        dyv0[q] = (iy >= j0y) ? iy - j0y : j0y - iy;
        dyv1[q] = (iy >= j1y) ? iy - j1y : j1y - iy;
    }

    f32x4 o1[4], o2[4];
    #pragma unroll
    for (int df = 0; df < 4; ++df) { o1[df] = (f32x4){0.f,0.f,0.f,0.f}; o2[df] = (f32x4){0.f,0.f,0.f,0.f}; }
    float m1 = -INFINITY, l1 = 0.0f, m2 = -INFINITY, l2 = 0.0f;

    const short* kbase = qk_t + (size_t)b * NTOK * 512 + 256 + h * DKK;
    const short* vbase = vvb + (size_t)(h * DVV) * 4096 + b * NTOK;
    const short* wtile = wmkb + (size_t)(h * 16) * 16384;   // +jc*16384 per tile

    // ---- prologue: tile 0 -> buf0 ; prefetch tile 1 into regs ----
    s16x8 stg[8];
    #pragma unroll
    for (int u = 0; u < 8; ++u)
        stg[u] = *(const s16x8*)(wtile + tid * 8 + u * 2048);
    #pragma unroll
    for (int u = 0; u < 8; ++u)
        *(s16x8*)&wmks[0][tid * 8 + u * 2048] = stg[u];
    #pragma unroll
    for (int u = 0; u < 8; ++u)
        stg[u] = *(const s16x8*)(wtile + 16384 + tid * 8 + u * 2048);
    __syncthreads();   // buf0 + pe_s/bmk_s ready

    for (int jc = 0; jc < 16; ++jc) {
        const int j0 = jc * 64;
        const int cur = jc & 1;
        const short* wbuf = wmks[cur];

        // ---- write tile jc+1 into the OTHER buffer; prefetch tile jc+2 ----
        if (jc < 15) {
            short* wdst = wmks[cur ^ 1];
            #pragma unroll
            for (int u = 0; u < 8; ++u)
                *(s16x8*)&wdst[tid * 8 + u * 2048] = stg[u];
            if (jc < 14) {
                #pragma unroll
                for (int u = 0; u < 8; ++u)
                    stg[u] = *(const s16x8*)(wtile + (size_t)(jc + 2) * 16384 + tid * 8 + u * 2048);
            }
        }

        // K and V fragments from global (L2-resident)
        s16x8 b2a[4], vf[2][4];
        #pragma unroll
        for (int df = 0; df < 4; ++df) {
            b2a[df] = *(const s16x8*)(kbase + (size_t)(j0 + df * 16 + l15) * 512 + lhi * 8);
            #pragma unroll
            for (int kt = 0; kt < 2; ++kt)
                vf[kt][df] = *(const s16x8*)(vbase + (size_t)(df * 16 + l15) * 4096 + j0 + kt * 32 + lhi * 8);
        }

        // ---- branch 1: S1^T = Wmk . q1^T  (K=256), linear frag reads ----
        f32x4 s1T[4];
        #pragma unroll
        for (int df = 0; df < 4; ++df) {
            f32x4 acc = {0.f, 0.f, 0.f, 0.f};
            #pragma unroll
            for (int ks = 0; ks < 8; ++ks) {
                s16x8 afr = *(const s16x8*)&wbuf[df * 4096 + ks * 512 + lane * 8];
                acc = __builtin_amdgcn_mfma_f32_16x16x32_bf16(afr, a1[ks], acc, 0, 0, 0);
            }
            s1T[df] = acc;
        }
        // ---- branch 2: S2^T = k~ . q^T  (K=32, SCALE pre-folded) ----
        f32x4 s2T[4];
        #pragma unroll
        for (int df = 0; df < 4; ++df) {
            f32x4 z = {0.f, 0.f, 0.f, 0.f};
            s2T[df] = __builtin_amdgcn_mfma_f32_16x16x32_bf16(b2a[df], a2, z, 0, 0, 0);
        }

        // bias for branch 1: bmk + pos_emb[|dx|,|dy|]*sqrt(32)
        {
            const int jx0 = j0 >> 5;
            int d0 = ix - jx0;     d0 = d0 < 0 ? -d0 : d0;
            int d1 = ix - jx0 - 1; d1 = d1 < 0 ? -d1 : d1;
            const float* per0 = pe_s + d0 * 32;
            const float* per1 = pe_s + d1 * 32;
            #pragma unroll
            for (int df = 0; df < 4; ++df) {
                f32x4 bm4 = *(const f32x4*)&bmk_s[j0 + df * 16 + lhi * 4];
                #pragma unroll
                for (int q = 0; q < 4; ++q) {
                    int dy = (df & 1) ? dyv1[q] : dyv0[q];
                    float pv = (df < 2) ? per0[dy] : per1[dy];
                    s1T[df][q] += bm4[q] + pv;
                }
            }
        }

        // ---- softmax branch 1 (defer-max, THR=8) ----
        unsigned pk1[4][2];
        {
            float mx = s1T[0][0];
            #pragma unroll
            for (int df = 0; df < 4; ++df)
                #pragma unroll
                for (int q = 0; q < 4; ++q) mx = fmaxf(mx, s1T[df][q]);
            mx = fmaxf(mx, __shfl_xor(mx, 16));
            mx = fmaxf(mx, __shfl_xor(mx, 32));
            float tm = fmaxf(m1, mx);
            if (!__all(tm - m1 <= 8.0f)) {
                float sc = __expf(m1 - tm);
                l1 *= sc;
                #pragma unroll
                for (int df = 0; df < 4; ++df) o1[df] *= sc;
                m1 = tm;
            }
            float rs = 0.f;
            #pragma unroll
            for (int df = 0; df < 4; ++df) {
                float p0 = __expf(s1T[df][0] - m1), p1 = __expf(s1T[df][1] - m1);
                float p2 = __expf(s1T[df][2] - m1), p3 = __expf(s1T[df][3] - m1);
                rs += (p0 + p1) + (p2 + p3);
                pk1[df][0] = cvt_pk_bf16(p0, p1);
                pk1[df][1] = cvt_pk_bf16(p2, p3);
            }
            rs += __shfl_xor(rs, 16);
            rs += __shfl_xor(rs, 32);
            l1 += rs;
        }
        // ---- softmax branch 2 ----
        unsigned pk2[4][2];
        {
            float mx = s2T[0][0];
            #pragma unroll
            for (int df = 0; df < 4; ++df)
                #pragma unroll
                for (int q = 0; q < 4; ++q) mx = fmaxf(mx, s2T[df][q]);
            mx = fmaxf(mx, __shfl_xor(mx, 16));
            mx = fmaxf(mx, __shfl_xor(mx, 32));
            float tm = fmaxf(m2, mx);
            if (!__all(tm - m2 <= 8.0f)) {
                float sc = __expf(m2 - tm);
                l2 *= sc;
                #pragma unroll
                for (int df = 0; df < 4; ++df) o2[df] *= sc;
                m2 = tm;
            }
            float rs = 0.f;
            #pragma unroll
            for (int df = 0; df < 4; ++df) {
                float p0 = __expf(s2T[df][0] - m2), p1 = __expf(s2T[df][1] - m2);
                float p2 = __expf(s2T[df][2] - m2), p3 = __expf(s2T[df][3] - m2);
                rs += (p0 + p1) + (p2 + p3);
                pk2[df][0] = cvt_pk_bf16(p0, p1);
                pk2[df][1] = cvt_pk_bf16(p2, p3);
            }
            rs += __shfl_xor(rs, 16);
            rs += __shfl_xor(rs, 32);
            l2 += rs;
        }

        // ---- PV: O^T += V^T . P^T ; in-register P redistribution ----
        const int srcA = l15 + ((lane & 16) << 1);   // l15 + 32*(lhi&1)
        const bool hi = (lane & 32) != 0;
        #pragma unroll
        for (int kt = 0; kt < 2; ++kt) {
            int x0 = __shfl((int)pk1[2*kt][0], srcA),      x1 = __shfl((int)pk1[2*kt+1][0], srcA);
            int y0 = __shfl((int)pk1[2*kt][1], srcA),      y1 = __shfl((int)pk1[2*kt+1][1], srcA);
            int z0 = __shfl((int)pk1[2*kt][0], srcA + 16), z1 = __shfl((int)pk1[2*kt+1][0], srcA + 16);
            int u0 = __shfl((int)pk1[2*kt][1], srcA + 16), u1 = __shfl((int)pk1[2*kt+1][1], srcA + 16);
            i32x4 bd1 = { hi ? x1 : x0, hi ? y1 : y0, hi ? z1 : z0, hi ? u1 : u0 };
            s16x8 pb1 = __builtin_bit_cast(s16x8, bd1);

            x0 = __shfl((int)pk2[2*kt][0], srcA);      x1 = __shfl((int)pk2[2*kt+1][0], srcA);
            y0 = __shfl((int)pk2[2*kt][1], srcA);      y1 = __shfl((int)pk2[2*kt+1][1], srcA);
            z0 = __shfl((int)pk2[2*kt][0], srcA + 16); z1 = __shfl((int)pk2[2*kt+1][0], srcA + 16);
            u0 = __shfl((int)pk2[2*kt][1], srcA + 16); u1 = __shfl((int)pk2[2*kt+1][1], srcA + 16);
            i32x4 bd2 = { hi ? x1 : x0, hi ? y1 : y0, hi ? z1 : z0, hi ? u1 : u0 };
            s16x8 pb2 = __builtin_bit_cast(s16x8, bd2);

            #pragma unroll
            for (int df = 0; df < 4; ++df)
                o1[df] = __builtin_amdgcn_mfma_f32_16x16x32_bf16(vf[kt][df], pb1, o1[df], 0, 0, 0);
            #pragma unroll
            for (int df = 0; df < 4; ++df)
                o2[df] = __builtin_amdgcn_mfma_f32_16x16x32_bf16(vf[kt][df], pb2, o2[df], 0, 0, 0);
        }

        __syncthreads();   // next-tile writes visible; current reads complete
    }

    // ---- epilogue: normalize, GELU, LDS-transpose, bf16 token-major store ----
    short* osw = wmks[0];               // overlay [64][72]
    #pragma unroll
    for (int pass = 0; pass < 2; ++pass) {
        __syncthreads();
        const int chbase = (pass ? 512 : 0) + h * DVV;
        const float inv = 1.0f / (pass ? l2 : l1);
        #pragma unroll
        for (int df = 0; df < 4; ++df)
            #pragma unroll
            for (int r = 0; r < 2; ++r) {
                float v0 = gelu((pass ? o2 : o1)[df][2*r]     * inv);
                float v1 = gelu((pass ? o2 : o1)[df][2*r + 1] * inv);
                unsigned d = cvt_pk_bf16(v0, v1);
                *(unsigned*)&osw[(w * 16 + l15) * 72 + df * 16 + lhi * 4 + 2 * r] = d;
            }
        __syncthreads();
        {
            int i = tid >> 2, cb = (tid & 3) * 16;
            s16x8 v0 = *(const s16x8*)&osw[i * 72 + cb];
            s16x8 v1 = *(const s16x8*)&osw[i * 72 + cb + 8];
            size_t dst = ((size_t)b * NTOK + i0 + i) * 1024 + chbase + cb;
            *(s16x8*)(gbuf + dst)     = v0;
            *(s16x8*)(gbuf + dst + 8) = v1;
        }
    }
}

// ---------------------------------------------------------------------------
// K3: out GEMM.  M=256 co, N=4096 tok, K=1024.  grid (128,8) = 1024 blocks
// (4/CU), block 256 (4 waves), tile 32co x 32tok, wave does 16x16.
// ---------------------------------------------------------------------------
__global__ __launch_bounds__(256) void out_mfma(
    const short* __restrict__ wob, const short* __restrict__ gbuf,
    const float* __restrict__ bo, const float* __restrict__ go,
    const float* __restrict__ bo2, float* __restrict__ out)
{
    const int t0 = blockIdx.x * 32;
    const int c0 = blockIdx.y * 32;
    const int tid  = threadIdx.x;
    const int w    = tid >> 6, lane = tid & 63;
    const int l15  = lane & 15, lhi = lane >> 4;
    const int cob = c0 + (w >> 1) * 16;
    const int tob = t0 + (w & 1) * 16;

    f32x4 acc = (f32x4){0.f, 0.f, 0.f, 0.f};

    #pragma unroll 4
    for (int ks = 0; ks < 32; ++ks) {
        s16x8 af = *(const s16x8*)(wob + (size_t)(cob + l15) * 1024 + ks * 32 + lhi * 8);
        s16x8 bf = *(const s16x8*)(gbuf + (size_t)(tob + l15) * 1024 + ks * 32 + lhi * 8);
        acc = __builtin_amdgcn_mfma_f32_16x16x32_bf16(af, bf, acc, 0, 0, 0);
    }

    const int gt = tob + l15;
    const int bb = gt >> 10, n = gt & 1023;
    #pragma unroll
    for (int q = 0; q < 4; ++q) {
        int co = cob + lhi * 4 + q;
        out[(size_t)bb * 262144 + (size_t)co * 1024 + n] =
            fmaf(acc[q] + bo[co], go[co], bo2[co]);
    }
}

// ---------------------------------------------------------------------------
extern "C" void kernel_launch(void* const* d_in, const int* in_sizes, int n_in,
                              void* d_out, int out_size, void* d_ws, size_t ws_size,
                              hipStream_t stream)
{
    const float* x    = (const float*)d_in[0];
    const float* Wq   = (const float*)d_in[1];
    const float* gq   = (const float*)d_in[2];
    const float* bq   = (const float*)d_in[3];
    const float* Wk   = (const float*)d_in[4];
    const float* gk   = (const float*)d_in[5];
    const float* bk   = (const float*)d_in[6];
    const float* Wv   = (const float*)d_in[7];
    const float* gv   = (const float*)d_in[8];
    const float* bv   = (const float*)d_in[9];
    const float* Wmk  = (const float*)d_in[10];
    const float* gmk  = (const float*)d_in[11];
    const float* bmk  = (const float*)d_in[12];
    const float* pe   = (const float*)d_in[13];
    const float* Wo   = (const float*)d_in[14];
    const float* bo   = (const float*)d_in[15];
    const float* go   = (const float*)d_in[16];
    const float* bo2  = (const float*)d_in[17];
    float* out = (float*)d_out;

    char* base = (char*)d_ws;
    short* xbt   = (short*)(base);                     //  2.0 MB
    short* wqkvb = (short*)(base + (2u  << 20));       //  0.5 MB
    short* wmkb  = (short*)(base + (3u  << 20));       //  4.0 MB
    short* wob   = (short*)(base + (7u  << 20));       //  0.5 MB
    short* qk_t  = (short*)(base + (8u  << 20));       //  4.0 MB
    short* vvb   = (short*)(base + (12u << 20));       //  4.0 MB
    short* gbuf  = (short*)(base + (16u << 20));       //  8.0 MB

    conv_all<<<dim3(1440), 256, 0, stream>>>(x, Wq, gq, Wk, gk, Wv, gv,
                                             Wmk, gmk, Wo, xbt, wqkvb, wmkb, wob);
    qkv_mfma<<<dim3(128, 8), 256, 0, stream>>>(wqkvb, xbt, bq, bk, bv, qk_t, vvb);
    attn_kernel<<<dim3(512), 256, 0, stream>>>(qk_t, vvb, wmkb, bmk, pe, gbuf);
    out_mfma<<<dim3(128, 8), 256, 0, stream>>>(wob, gbuf, bo, go, bo2, out);
}

// Round 16
// 122.301 us; speedup vs baseline: 1.1828x; 1.0007x over previous
//
#include <hip/hip_runtime.h>

#define NHEADS 8
#define DKK    32
#define DVV    64
#define NTOK   1024
#define DIM    256

typedef float  f32x4 __attribute__((ext_vector_type(4)));
typedef short  s16x4 __attribute__((ext_vector_type(4)));
typedef short  s16x8 __attribute__((ext_vector_type(8)));
typedef int    i32x4 __attribute__((ext_vector_type(4)));

#define SCALE_QK 0.17677669529663687f   /* 32^-0.5 */

__device__ __forceinline__ unsigned short f2bf(float f) {
    unsigned u = __builtin_bit_cast(unsigned, f);
    u += 0x7FFFu + ((u >> 16) & 1u);          // RNE
    return (unsigned short)(u >> 16);
}

__device__ __forceinline__ unsigned cvt_pk_bf16(float lo, float hi) {
    unsigned r;
    asm("v_cvt_pk_bf16_f32 %0, %1, %2" : "=v"(r) : "v"(lo), "v"(hi));
    return r;
}

__device__ __forceinline__ float gelu(float v) {
    return 0.5f * v * (1.0f + erff(v * 0.70710678118654752f));
}

// ---------------------------------------------------------------------------
// C (fused): input + weight converts, one launch, 1440 blocks.
//  blocks [0,256):     x [b][256][1024] f32 -> xbt [4096 tok][256] bf16
//  blocks [256,384):   wqkvb[1024][256], gamma-folded; k rows * SCALE_QK
//  blocks [384,1408):  wmkb fragment-order, gmk-folded
//  blocks [1408,1440): wob[256][1024]
// ---------------------------------------------------------------------------
__global__ __launch_bounds__(256) void conv_all(
    const float* __restrict__ x,
    const float* __restrict__ Wq, const float* __restrict__ gq,
    const float* __restrict__ Wk, const float* __restrict__ gk,
    const float* __restrict__ Wv, const float* __restrict__ gv,
    const float* __restrict__ Wmk, const float* __restrict__ gmk,
    const float* __restrict__ Wo,
    short* __restrict__ xbt, short* __restrict__ wqkvb,
    short* __restrict__ wmkb, short* __restrict__ wob)
{
    __shared__ short tl[64 * 72];
    const int bid = blockIdx.x;
    const int tid = threadIdx.x;
    if (bid < 256) {
        const int n0 = (bid & 15) * 64, c0 = ((bid >> 4) & 3) * 64, b = bid >> 6;
        #pragma unroll
        for (int s = 0; s < 16; ++s) {
            int id = tid + s * 256;
            int cc = id >> 6, nn = id & 63;
            tl[nn * 72 + cc] = (short)f2bf(x[(size_t)b * 262144 + (size_t)(c0 + cc) * 1024 + n0 + nn]);
        }
        __syncthreads();
        #pragma unroll
        for (int s = 0; s < 2; ++s) {
            int id = tid + s * 256;
            int nn = id >> 3, c8 = id & 7;
            *(s16x8*)(xbt + ((size_t)b * 1024 + n0 + nn) * 256 + c0 + c8 * 8) =
                *(const s16x8*)&tl[nn * 72 + c8 * 8];
        }
    } else if (bid < 384) {
        const int sub = tid >> 5;
        const int row = (bid - 256) * 8 + sub;
        const int c0  = (tid & 31) * 8;
        float g; const float* src;
        if (row < 256)      { g = gq[row];                  src = Wq + (size_t)row * DIM; }
        else if (row < 512) { g = gk[row - 256] * SCALE_QK; src = Wk + (size_t)(row - 256) * DIM; }
        else                { g = gv[row - 512];            src = Wv + (size_t)(row - 512) * DIM; }
        float4 x0 = *(const float4*)(src + c0);
        float4 x1 = *(const float4*)(src + c0 + 4);
        s16x8 o;
        o[0] = (short)f2bf(g * x0.x); o[1] = (short)f2bf(g * x0.y);
        o[2] = (short)f2bf(g * x0.z); o[3] = (short)f2bf(g * x0.w);
        o[4] = (short)f2bf(g * x1.x); o[5] = (short)f2bf(g * x1.y);
        o[6] = (short)f2bf(g * x1.z); o[7] = (short)f2bf(g * x1.w);
        *(s16x8*)(wqkvb + (size_t)row * DIM + c0) = o;
    } else if (bid < 1408) {
        const int gid = (bid - 384) * 256 + tid;           // 0..262143
        const int c   = gid & 2047;
        const int t   = (gid >> 11) & 15;
        const int h   = gid >> 15;
        const int df  = c >> 9, ks = (c >> 6) & 7, ln = c & 63;
        const int l15 = ln & 15, lhi = ln >> 4;
        const int row = h * 1024 + t * 64 + df * 16 + l15;
        const int col = ks * 32 + lhi * 8;
        const float g = gmk[row];
        const float* src = Wmk + (size_t)row * DIM + col;
        float4 x0 = *(const float4*)(src);
        float4 x1 = *(const float4*)(src + 4);
        s16x8 o;
        o[0] = (short)f2bf(g * x0.x); o[1] = (short)f2bf(g * x0.y);
        o[2] = (short)f2bf(g * x0.z); o[3] = (short)f2bf(g * x0.w);
        o[4] = (short)f2bf(g * x1.x); o[5] = (short)f2bf(g * x1.y);
        o[6] = (short)f2bf(g * x1.z); o[7] = (short)f2bf(g * x1.w);
        *(s16x8*)(wmkb + (size_t)gid * 8) = o;
    } else {
        const int sub = tid >> 5;
        const int row = (bid - 1408) * 8 + sub;
        const int l   = tid & 31;
        #pragma unroll
        for (int u = 0; u < 4; ++u) {
            int c = l * 8 + u * 256;
            const float* src = Wo + (size_t)row * 1024 + c;
            float4 x0 = *(const float4*)(src);
            float4 x1 = *(const float4*)(src + 4);
            s16x8 o;
            o[0] = (short)f2bf(x0.x); o[1] = (short)f2bf(x0.y);
            o[2] = (short)f2bf(x0.z); o[3] = (short)f2bf(x0.w);
            o[4] = (short)f2bf(x1.x); o[5] = (short)f2bf(x1.y);
            o[6] = (short)f2bf(x1.z); o[7] = (short)f2bf(x1.w);
            *(s16x8*)(wob + (size_t)row * 1024 + c) = o;
        }
    }
}

// ---------------------------------------------------------------------------
// K1: qkv GEMM.  M=1024 ch, N=4096 tok, K=256.  grid (128,8), 256 thr.
// ---------------------------------------------------------------------------
__global__ __launch_bounds__(256) void qkv_mfma(
    const short* __restrict__ wqkvb, const short* __restrict__ xbt,
    const float* __restrict__ bq, const float* __restrict__ bk,
    const float* __restrict__ bv,
    short* __restrict__ qk_t, short* __restrict__ vvb)
{
    __shared__ __align__(16) short tlds[32 * 136];   // 8,704 B

    const int t0 = blockIdx.x * 32;
    const int c0 = blockIdx.y * 128;
    const int tid  = threadIdx.x;
    const int w    = tid >> 6, lane = tid & 63;
    const int l15  = lane & 15, lhi = lane >> 4;
    const int cob = c0 + w * 32;

    f32x4 acc[2][2];
    #pragma unroll
    for (int mf = 0; mf < 2; ++mf)
        #pragma unroll
        for (int nf = 0; nf < 2; ++nf) acc[mf][nf] = (f32x4){0.f, 0.f, 0.f, 0.f};

    #pragma unroll
    for (int ks = 0; ks < 8; ++ks) {
        s16x8 af[2], bf[2];
        #pragma unroll
        for (int mf = 0; mf < 2; ++mf)
            af[mf] = *(const s16x8*)(wqkvb + (size_t)(cob + mf * 16 + l15) * DIM + ks * 32 + lhi * 8);
        #pragma unroll
        for (int nf = 0; nf < 2; ++nf)
            bf[nf] = *(const s16x8*)(xbt + (size_t)(t0 + nf * 16 + l15) * DIM + ks * 32 + lhi * 8);
        #pragma unroll
        for (int mf = 0; mf < 2; ++mf)
            #pragma unroll
            for (int nf = 0; nf < 2; ++nf)
                acc[mf][nf] = __builtin_amdgcn_mfma_f32_16x16x32_bf16(af[mf], bf[nf], acc[mf][nf], 0, 0, 0);
    }

    float bias[2][4];
    #pragma unroll
    for (int mf = 0; mf < 2; ++mf)
        #pragma unroll
        for (int q = 0; q < 4; ++q) {
            int ch = cob + mf * 16 + lhi * 4 + q;
            bias[mf][q] = (ch < 256) ? bq[ch]
                        : (ch < 512) ? bk[ch - 256] * SCALE_QK
                                     : bv[ch - 512];
        }

    if (c0 < 512) {
        #pragma unroll
        for (int mf = 0; mf < 2; ++mf)
            #pragma unroll
            for (int nf = 0; nf < 2; ++nf) {
                s16x4 pk;
                #pragma unroll
                for (int q = 0; q < 4; ++q)
                    pk[q] = (short)f2bf(acc[mf][nf][q] + bias[mf][q]);
                *(s16x4*)&tlds[(nf * 16 + l15) * 136 + w * 32 + mf * 16 + lhi * 4] = pk;
            }
        __syncthreads();
        #pragma unroll
        for (int s = 0; s < 2; ++s) {
            int id = tid + s * 256;
            int tok = id >> 4, c8 = id & 15;
            *(s16x8*)(qk_t + (size_t)(t0 + tok) * 512 + c0 + c8 * 8) =
                *(const s16x8*)&tlds[tok * 136 + c8 * 8];
        }
    } else {
        #pragma unroll
        for (int mf = 0; mf < 2; ++mf)
            #pragma unroll
            for (int nf = 0; nf < 2; ++nf) {
                int gt = t0 + nf * 16 + l15;
                #pragma unroll
                for (int q = 0; q < 4; ++q) {
                    int vch = cob + mf * 16 + lhi * 4 + q - 512;
                    vvb[(size_t)vch * 4096 + gt] = (short)f2bf(acc[mf][nf][q] + bias[mf][q]);
                }
            }
    }
}

// ---------------------------------------------------------------------------
// K2: fused dual-branch flash attention (proven config, locked in).
// Online softmax, defer-rescale THR=8.  Double-buffered fragment-order Wmk,
// one barrier per jc.  grid 512, block 256, 2 blocks/CU.
// ---------------------------------------------------------------------------
__global__ __launch_bounds__(256, 2) void attn_kernel(
    const short* __restrict__ qk_t, const short* __restrict__ vvb,
    const short* __restrict__ wmkb, const float* __restrict__ bmk,
    const float* __restrict__ pos_emb, short* __restrict__ gbuf)
{
    __shared__ __align__(16) short wmks[2][16384];   // 65,536 B (2x frag-order)
    __shared__ float pe_s[1024];                     //  4,096 B
    __shared__ float bmk_s[1024];                    //  4,096 B  = 73,728 total

    const int flat = blockIdx.x;
    const int h  = flat & 7;
    const int it = (flat >> 3) & 15;
    const int b  = flat >> 7;
    const int i0 = it * 64;
    const int tid = threadIdx.x;
    const int w = tid >> 6, lane = tid & 63;
    const int l15 = lane & 15, lhi = lane >> 4;

    for (int p = tid; p < 1024; p += 256) {
        pe_s[p]  = pos_emb[p * NHEADS + h] * 5.656854249492380f;  // * sqrt(32)
        bmk_s[p] = bmk[h * NTOK + p];
    }

    // Q fragments (B-operands): one i-row per lane
    const int irow = i0 + w * 16 + l15;
    const short* q1row = qk_t + ((size_t)b * NTOK + irow) * 512;
    s16x8 a1[8];
    #pragma unroll
    for (int ks = 0; ks < 8; ++ks)
        a1[ks] = *(const s16x8*)(q1row + ks * 32 + lhi * 8);
    s16x8 a2 = *(const s16x8*)(q1row + h * DKK + lhi * 8);

    const int ix = irow >> 5, iy = irow & 31;
    int dyv0[4], dyv1[4];
    #pragma unroll
    for (int q = 0; q < 4; ++q) {
        int j0y = lhi * 4 + q, j1y = 16 + lhi * 4 + q;
        dyv0[q] = (iy >= j0y) ? iy - j0y : j0y - iy;
        dyv1[q] = (iy >= j1y) ? iy - j1y : j1y - iy;
    }

    f32x4 o1[4], o2[4];
    #pragma unroll
    for (int df = 0; df < 4; ++df) { o1[df] = (f32x4){0.f,0.f,0.f,0.f}; o2[df] = (f32x4){0.f,0.f,0.f,0.f}; }
    float m1 = -INFINITY, l1 = 0.0f, m2 = -INFINITY, l2 = 0.0f;

    const short* kbase = qk_t + (size_t)b * NTOK * 512 + 256 + h * DKK;
    const short* vbase = vvb + (size_t)(h * DVV) * 4096 + b * NTOK;
    const short* wtile = wmkb + (size_t)(h * 16) * 16384;   // +jc*16384 per tile

    // ---- prologue: tile 0 -> buf0 ; prefetch tile 1 into regs ----
    s16x8 stg[8];
    #pragma unroll
    for (int u = 0; u < 8; ++u)
        stg[u] = *(const s16x8*)(wtile + tid * 8 + u * 2048);
    #pragma unroll
    for (int u = 0; u < 8; ++u)
        *(s16x8*)&wmks[0][tid * 8 + u * 2048] = stg[u];
    #pragma unroll
    for (int u = 0; u < 8; ++u)
        stg[u] = *(const s16x8*)(wtile + 16384 + tid * 8 + u * 2048);
    __syncthreads();   // buf0 + pe_s/bmk_s ready

    for (int jc = 0; jc < 16; ++jc) {
        const int j0 = jc * 64;
        const int cur = jc & 1;
        const short* wbuf = wmks[cur];

        // ---- write tile jc+1 into the OTHER buffer; prefetch tile jc+2 ----
        if (jc < 15) {
            short* wdst = wmks[cur ^ 1];
            #pragma unroll
            for (int u = 0; u < 8; ++u)
                *(s16x8*)&wdst[tid * 8 + u * 2048] = stg[u];
            if (jc < 14) {
                #pragma unroll
                for (int u = 0; u < 8; ++u)
                    stg[u] = *(const s16x8*)(wtile + (size_t)(jc + 2) * 16384 + tid * 8 + u * 2048);
            }
        }

        // K and V fragments from global (L2-resident)
        s16x8 b2a[4], vf[2][4];
        #pragma unroll
        for (int df = 0; df < 4; ++df) {
            b2a[df] = *(const s16x8*)(kbase + (size_t)(j0 + df * 16 + l15) * 512 + lhi * 8);
            #pragma unroll
            for (int kt = 0; kt < 2; ++kt)
                vf[kt][df] = *(const s16x8*)(vbase + (size_t)(df * 16 + l15) * 4096 + j0 + kt * 32 + lhi * 8);
        }

        // ---- branch 1: S1^T = Wmk . q1^T  (K=256), linear frag reads ----
        f32x4 s1T[4];
        #pragma unroll
        for (int df = 0; df < 4; ++df) {
            f32x4 acc = {0.f, 0.f, 0.f, 0.f};
            #pragma unroll
            for (int ks = 0; ks < 8; ++ks) {
                s16x8 afr = *(const s16x8*)&wbuf[df * 4096 + ks * 512 + lane * 8];
                acc = __builtin_amdgcn_mfma_f32_16x16x32_bf16(afr, a1[ks], acc, 0, 0, 0);
            }
            s1T[df] = acc;
        }
        // ---- branch 2: S2^T = k~ . q^T  (K=32, SCALE pre-folded) ----
        f32x4 s2T[4];
        #pragma unroll
        for (int df = 0; df < 4; ++df) {
            f32x4 z = {0.f, 0.f, 0.f, 0.f};
            s2T[df] = __builtin_amdgcn_mfma_f32_16x16x32_bf16(b2a[df], a2, z, 0, 0, 0);
        }

        // bias for branch 1: bmk + pos_emb[|dx|,|dy|]*sqrt(32)
        {
            const int jx0 = j0 >> 5;
            int d0 = ix - jx0;     d0 = d0 < 0 ? -d0 : d0;
            int d1 = ix - jx0 - 1; d1 = d1 < 0 ? -d1 : d1;
            const float* per0 = pe_s + d0 * 32;
            const float* per1 = pe_s + d1 * 32;
            #pragma unroll
            for (int df = 0; df < 4; ++df) {
                f32x4 bm4 = *(const f32x4*)&bmk_s[j0 + df * 16 + lhi * 4];
                #pragma unroll
                for (int q = 0; q < 4; ++q) {
                    int dy = (df & 1) ? dyv1[q] : dyv0[q];
                    float pv = (df < 2) ? per0[dy] : per1[dy];
                    s1T[df][q] += bm4[q] + pv;
                }
            }
        }

        // ---- softmax branch 1 (defer-max, THR=8) ----
        unsigned pk1[4][2];
        {
            float mx = s1T[0][0];
            #pragma unroll
            for (int df = 0; df < 4; ++df)
                #pragma unroll
                for (int q = 0; q < 4; ++q) mx = fmaxf(mx, s1T[df][q]);
            mx = fmaxf(mx, __shfl_xor(mx, 16));
            mx = fmaxf(mx, __shfl_xor(mx, 32));
            float tm = fmaxf(m1, mx);
            if (!__all(tm - m1 <= 8.0f)) {
                float sc = __expf(m1 - tm);
                l1 *= sc;
                #pragma unroll
                for (int df = 0; df < 4; ++df) o1[df] *= sc;
                m1 = tm;
            }
            float rs = 0.f;
            #pragma unroll
            for (int df = 0; df < 4; ++df) {
                float p0 = __expf(s1T[df][0] - m1), p1 = __expf(s1T[df][1] - m1);
                float p2 = __expf(s1T[df][2] - m1), p3 = __expf(s1T[df][3] - m1);
                rs += (p0 + p1) + (p2 + p3);
                pk1[df][0] = cvt_pk_bf16(p0, p1);
                pk1[df][1] = cvt_pk_bf16(p2, p3);
            }
            rs += __shfl_xor(rs, 16);
            rs += __shfl_xor(rs, 32);
            l1 += rs;
        }
        // ---- softmax branch 2 ----
        unsigned pk2[4][2];
        {
            float mx = s2T[0][0];
            #pragma unroll
            for (int df = 0; df < 4; ++df)
                #pragma unroll
                for (int q = 0; q < 4; ++q) mx = fmaxf(mx, s2T[df][q]);
            mx = fmaxf(mx, __shfl_xor(mx, 16));
            mx = fmaxf(mx, __shfl_xor(mx, 32));
            float tm = fmaxf(m2, mx);
            if (!__all(tm - m2 <= 8.0f)) {
                float sc = __expf(m2 - tm);
                l2 *= sc;
                #pragma unroll
                for (int df = 0; df < 4; ++df) o2[df] *= sc;
                m2 = tm;
            }
            float rs = 0.f;
            #pragma unroll
            for (int df = 0; df < 4; ++df) {
                float p0 = __expf(s2T[df][0] - m2), p1 = __expf(s2T[df][1] - m2);
                float p2 = __expf(s2T[df][2] - m2), p3 = __expf(s2T[df][3] - m2);
                rs += (p0 + p1) + (p2 + p3);
                pk2[df][0] = cvt_pk_bf16(p0, p1);
                pk2[df][1] = cvt_pk_bf16(p2, p3);
            }
            rs += __shfl_xor(rs, 16);
            rs += __shfl_xor(rs, 32);
            l2 += rs;
        }

        // ---- PV: O^T += V^T . P^T ; in-register P redistribution ----
        const int srcA = l15 + ((lane & 16) << 1);   // l15 + 32*(lhi&1)
        const bool hi = (lane & 32) != 0;
        #pragma unroll
        for (int kt = 0; kt < 2; ++kt) {
            int x0 = __shfl((int)pk1[2*kt][0], srcA),      x1 = __shfl((int)pk1[2*kt+1][0], srcA);
            int y0 = __shfl((int)pk1[2*kt][1], srcA),      y1 = __shfl((int)pk1[2*kt+1][1], srcA);
            int z0 = __shfl((int)pk1[2*kt][0], srcA + 16), z1 = __shfl((int)pk1[2*kt+1][0], srcA + 16);
            int u0 = __shfl((int)pk1[2*kt][1], srcA + 16), u1 = __shfl((int)pk1[2*kt+1][1], srcA + 16);
            i32x4 bd1 = { hi ? x1 : x0, hi ? y1 : y0, hi ? z1 : z0, hi ? u1 : u0 };
            s16x8 pb1 = __builtin_bit_cast(s16x8, bd1);

            x0 = __shfl((int)pk2[2*kt][0], srcA);      x1 = __shfl((int)pk2[2*kt+1][0], srcA);
            y0 = __shfl((int)pk2[2*kt][1], srcA);      y1 = __shfl((int)pk2[2*kt+1][1], srcA);
            z0 = __shfl((int)pk2[2*kt][0], srcA + 16); z1 = __shfl((int)pk2[2*kt+1][0], srcA + 16);
            u0 = __shfl((int)pk2[2*kt][1], srcA + 16); u1 = __shfl((int)pk2[2*kt+1][1], srcA + 16);
            i32x4 bd2 = { hi ? x1 : x0, hi ? y1 : y0, hi ? z1 : z0, hi ? u1 : u0 };
            s16x8 pb2 = __builtin_bit_cast(s16x8, bd2);

            #pragma unroll
            for (int df = 0; df < 4; ++df)
                o1[df] = __builtin_amdgcn_mfma_f32_16x16x32_bf16(vf[kt][df], pb1, o1[df], 0, 0, 0);
            #pragma unroll
            for (int df = 0; df < 4; ++df)
                o2[df] = __builtin_amdgcn_mfma_f32_16x16x32_bf16(vf[kt][df], pb2, o2[df], 0, 0, 0);
        }

        __syncthreads();   // next-tile writes visible; current reads complete
    }

    // ---- epilogue: normalize, GELU, LDS-transpose, bf16 token-major store ----
    short* osw = wmks[0];               // overlay [64][72]
    #pragma unroll
    for (int pass = 0; pass < 2; ++pass) {
        __syncthreads();
        const int chbase = (pass ? 512 : 0) + h * DVV;
        const float inv = 1.0f / (pass ? l2 : l1);
        #pragma unroll
        for (int df = 0; df < 4; ++df)
            #pragma unroll
            for (int r = 0; r < 2; ++r) {
                float v0 = gelu((pass ? o2 : o1)[df][2*r]     * inv);
                float v1 = gelu((pass ? o2 : o1)[df][2*r + 1] * inv);
                unsigned d = cvt_pk_bf16(v0, v1);
                *(unsigned*)&osw[(w * 16 + l15) * 72 + df * 16 + lhi * 4 + 2 * r] = d;
            }
        __syncthreads();
        {
            int i = tid >> 2, cb = (tid & 3) * 16;
            s16x8 v0 = *(const s16x8*)&osw[i * 72 + cb];
            s16x8 v1 = *(const s16x8*)&osw[i * 72 + cb + 8];
            size_t dst = ((size_t)b * NTOK + i0 + i) * 1024 + chbase + cb;
            *(s16x8*)(gbuf + dst)     = v0;
            *(s16x8*)(gbuf + dst + 8) = v1;
        }
    }
}

// ---------------------------------------------------------------------------
// K3: out GEMM.  M=256 co, N=4096 tok, K=1024.  grid (128,8) = 1024 blocks
// (4/CU), block 256 (4 waves), tile 32co x 32tok, wave does 16x16.
// ---------------------------------------------------------------------------
__global__ __launch_bounds__(256) void out_mfma(
    const short* __restrict__ wob, const short* __restrict__ gbuf,
    const float* __restrict__ bo, const float* __restrict__ go,
    const float* __restrict__ bo2, float* __restrict__ out)
{
    const int t0 = blockIdx.x * 32;
    const int c0 = blockIdx.y * 32;
    const int tid  = threadIdx.x;
    const int w    = tid >> 6, lane = tid & 63;
    const int l15  = lane & 15, lhi = lane >> 4;
    const int cob = c0 + (w >> 1) * 16;
    const int tob = t0 + (w & 1) * 16;

    f32x4 acc = (f32x4){0.f, 0.f, 0.f, 0.f};

    #pragma unroll 4
    for (int ks = 0; ks < 32; ++ks) {
        s16x8 af = *(const s16x8*)(wob + (size_t)(cob + l15) * 1024 + ks * 32 + lhi * 8);
        s16x8 bf = *(const s16x8*)(gbuf + (size_t)(tob + l15) * 1024 + ks * 32 + lhi * 8);
        acc = __builtin_amdgcn_mfma_f32_16x16x32_bf16(af, bf, acc, 0, 0, 0);
    }

    const int gt = tob + l15;
    const int bb = gt >> 10, n = gt & 1023;
    #pragma unroll
    for (int q = 0; q < 4; ++q) {
        int co = cob + lhi * 4 + q;
        out[(size_t)bb * 262144 + (size_t)co * 1024 + n] =
            fmaf(acc[q] + bo[co], go[co], bo2[co]);
    }
}

// ---------------------------------------------------------------------------
extern "C" void kernel_launch(void* const* d_in, const int* in_sizes, int n_in,
                              void* d_out, int out_size, void* d_ws, size_t ws_size,
                              hipStream_t stream)
{
    const float* x    = (const float*)d_in[0];
    const float* Wq   = (const float*)d_in[1];
    const float* gq   = (const float*)d_in[2];
    const float* bq   = (const float*)d_in[3];
    const float* Wk   = (const float*)d_in[4];
    const float* gk   = (const float*)d_in[5];
    const float* bk   = (const float*)d_in[6];
    const float* Wv   = (const float*)d_in[7];
    const float* gv   = (const float*)d_in[8];
    const float* bv   = (const float*)d_in[9];
    const float* Wmk  = (const float*)d_in[10];
    const float* gmk  = (const float*)d_in[11];
    const float* bmk  = (const float*)d_in[12];
    const float* pe   = (const float*)d_in[13];
    const float* Wo   = (const float*)d_in[14];
    const float* bo   = (const float*)d_in[15];
    const float* go   = (const float*)d_in[16];
    const float* bo2  = (const float*)d_in[17];
    float* out = (float*)d_out;

    char* base = (char*)d_ws;
    short* xbt   = (short*)(base);                     //  2.0 MB
    short* wqkvb = (short*)(base + (2u  << 20));       //  0.5 MB
    short* wmkb  = (short*)(base + (3u  << 20));       //  4.0 MB
    short* wob   = (short*)(base + (7u  << 20));       //  0.5 MB
    short* qk_t  = (short*)(base + (8u  << 20));       //  4.0 MB
    short* vvb   = (short*)(base + (12u << 20));       //  4.0 MB
    short* gbuf  = (short*)(base + (16u << 20));       //  8.0 MB

    conv_all<<<dim3(1440), 256, 0, stream>>>(x, Wq, gq, Wk, gk, Wv, gv,
                                             Wmk, gmk, Wo, xbt, wqkvb, wmkb, wob);
    qkv_mfma<<<dim3(128, 8), 256, 0, stream>>>(wqkvb, xbt, bq, bk, bv, qk_t, vvb);
    attn_kernel<<<dim3(512), 256, 0, stream>>>(qk_t, vvb, wmkb, bmk, pe, gbuf);
    out_mfma<<<dim3(128, 8), 256, 0, stream>>>(wob, gbuf, bo, go, bo2, out);
}